// Round 2
// baseline (1052.686 us; speedup 1.0000x reference)
//
#include <hip/hip_runtime.h>
#include <math.h>

// Problem constants (N=80000, Rr=5, A=8, D=32, T=32, K=8 rotations, ROT_DELTA=1)
#define RR 5
#define AA 8
#define DD 32
#define TT 32
#define KK 8

#define RT2 0.70710678118654752f

typedef float v2f __attribute__((ext_vector_type(2)));
typedef float v4f __attribute__((ext_vector_type(4)));

static __device__ __forceinline__ v2f pkfma(v2f a, v2f b, v2f c) {
#if __has_builtin(__builtin_elementwise_fma)
    return __builtin_elementwise_fma(a, b, c);
#else
    v2f r; r.x = fmaf(a.x, b.x, c.x); r.y = fmaf(a.y, b.y, c.y); return r;
#endif
}
static __device__ __forceinline__ v2f pkfmas(v2f a, float s, v2f c) {
    v2f b = {s, s};
    return pkfma(a, b, c);
}
static __device__ __forceinline__ v4f pkfma4(v4f a, v4f b, v4f c) {
#if __has_builtin(__builtin_elementwise_fma)
    return __builtin_elementwise_fma(a, b, c);
#else
    v4f r;
    r.x = fmaf(a.x, b.x, c.x); r.y = fmaf(a.y, b.y, c.y);
    r.z = fmaf(a.z, b.z, c.z); r.w = fmaf(a.w, b.w, c.w);
    return r;
#endif
}

// ---------------------------------------------------------------------------
// prep: zero stats workspace + W spectral precompute for BOTH layers.
// Ws layout (for wave-uniform s_load in the GEMM):
//   Ws[(((r*32 + d)*4 + wq)*64) + tq*8 + f]   with t = wq*8 + tq,
//   f-pack = {F0,F4,R1,I1, R2,I2,R3,I3}.
// Per (r, d, wave) the 64-float slice is contiguous & 256B-aligned ->
// 4 x s_load_dwordx16.
// grid = 40 blocks: 0..19 -> W1, 20..39 -> W2. One thread per (t,r,d).
// ---------------------------------------------------------------------------
__global__ void prep_kernel(const float* __restrict__ W1, const float* __restrict__ W2,
                            float* __restrict__ Ws1, float* __restrict__ Ws2,
                            double* __restrict__ dz, float* __restrict__ fz) {
    int b = blockIdx.x;
    int tid = threadIdx.x;
    if (b == 0 && tid < 128) { dz[tid] = 0.0; fz[tid] = 0.f; }
    int which = (b >= 20) ? 1 : 0;
    const float* __restrict__ W = which ? W2 : W1;
    float* __restrict__ Ws = which ? Ws2 : Ws1;
    int idx = (b - which * 20) * 256 + tid;
    if (idx >= TT * RR * DD) return;
    int d = idx & 31;
    int tr = idx >> 5;      // t*5+r
    int t = tr / 5;
    int r = tr - t * 5;
    float xa[8];
    #pragma unroll
    for (int a = 0; a < 8; ++a) xa[a] = W[(tr * 8 + a) * 32 + d];
    float s0 = xa[0] + xa[4], d0 = xa[0] - xa[4];
    float s1 = xa[1] + xa[5], d1 = xa[1] - xa[5];
    float s2 = xa[2] + xa[6], d2 = xa[2] - xa[6];
    float s3 = xa[3] + xa[7], d3 = xa[3] - xa[7];
    float s02 = s0 + s2, s13 = s1 + s3;
    float F0 = s02 + s13, F4 = s02 - s13;
    float R2 = s0 - s2, I2 = s3 - s1;
    float u = RT2 * (d1 - d3), v = RT2 * (d1 + d3);
    float R1 = d0 + u, R3 = d0 - u;
    float I1 = -d2 - v, I3 = d2 - v;
    int wq = t >> 3, tq = t & 7;
    float* o = &Ws[(size_t)((((r * 32 + d) * 4 + wq) * 64) + tq * 8)];
    *(v4f*)&o[0] = (v4f){F0, F4, R1, I1};
    *(v4f*)&o[4] = (v4f){R2, I2, R3, I3};
}

// ---------------------------------------------------------------------------
// Fused kernel: gather + barycentric interp + forward DFT8 + spectral GEMM
// (W in SGPRs via s_load) + IDFT8 + bias + angular max pool + fused BN stats.
//
// Block = 256 threads (4 waves), 64 vertices/block.
// GEMM mapping: wave wv owns templates t in [wv*8, wv*8+8) (wave-uniform ->
// W comes from scalar loads, zero LDS and a free broadcast as the 1-SGPR
// source of v_pk_fma_f32); lane owns one vertex. Per (lane, dl): 2 x
// ds_read_b128 feed 56 pk_fma (6x fewer LDS instrs than the Wl scheme),
// and the W staging + 8 of the 10 barriers per r disappear.
// Pooling needs a cross-wave norm reduce: 8 KB LDS scratch (NrmS).
// ---------------------------------------------------------------------------
__global__ __launch_bounds__(256, 2)
void fused_conv_kernel(const float* __restrict__ sig,
                       const int* __restrict__ bc_idx,
                       const float* __restrict__ bc_w,
                       const float* __restrict__ Wsg,
                       const float* __restrict__ bias,
                       float* __restrict__ s_out,
                       double* __restrict__ sums,
                       double* __restrict__ sumsq,
                       int N) {
    __shared__ float Is[64 * 260];     // 66560 B spectral interp, stride 260
    __shared__ float NrmS[4 * 64 * 8]; // 8192 B cross-wave norm partials

    int tid = threadIdx.x;
    int vBase = blockIdx.x * 64;
    int lane = tid & 63;
    int wv = tid >> 6;
    int wvu = __builtin_amdgcn_readfirstlane(wv);  // provably wave-uniform

    // gather-phase lane roles (v4f granularity, 8 lanes per vertex row)
    int d4 = tid & 7;                // floats 4*d4 .. 4*d4+3
    int g = tid >> 3;                // 0..31

    // GEMM/epilogue roles: lane <-> local vertex
    int vL = lane;
    int v = vBase + vL;

    // spectral accumulators per tq (t = wvu*8 + tq):
    // A0=(C0,C4) A1=(R1,I1) A2=(R2,I2) A3=(R3,I3)
    v2f A0[8], A1[8], A2[8], A3[8];
    #pragma unroll
    for (int tq = 0; tq < 8; ++tq) {
        A0[tq] = (v2f){0.f, 0.f}; A1[tq] = (v2f){0.f, 0.f};
        A2[tq] = (v2f){0.f, 0.f}; A3[tq] = (v2f){0.f, 0.f};
    }

    for (int r = 0; r < RR; ++r) {
        __syncthreads();  // previous r's GEMM done with Is

        // ---- gather + interp + forward DFT8 -> Is ----
        #pragma unroll
        for (int vv0 = 0; vv0 < 2; ++vv0) {
            int vv = g + vv0 * 32;           // 0..63
            int vgl = vBase + vv;
            int vgc = (vgl < N) ? vgl : (N - 1);
            int base = vgc * 120 + r * 24;   // 16B-aligned (480*v + 96*r bytes)
            int idxv[24]; float wbc[24];
            const int4* ib = (const int4*)(bc_idx + base);
            const float4* fb = (const float4*)(bc_w + base);
            #pragma unroll
            for (int q = 0; q < 6; ++q) {
                *(int4*)&idxv[q * 4] = ib[q];
                *(float4*)&wbc[q * 4] = fb[q];
            }
            v4f xa[8];
            #pragma unroll
            for (int a = 0; a < 8; ++a) {
                int i0 = idxv[a * 3 + 0];
                int i1 = idxv[a * 3 + 1];
                int i2 = idxv[a * 3 + 2];
                v4f r0 = *(const v4f*)&sig[(size_t)i0 * 32 + 4 * d4];
                v4f r1 = *(const v4f*)&sig[(size_t)i1 * 32 + 4 * d4];
                v4f r2 = *(const v4f*)&sig[(size_t)i2 * 32 + 4 * d4];
                float w0 = wbc[a * 3 + 0];
                float w1 = wbc[a * 3 + 1];
                float w2 = wbc[a * 3 + 2];
                v4f w0v = (v4f){w0, w0, w0, w0};
                v4f w1v = (v4f){w1, w1, w1, w1};
                v4f w2v = (v4f){w2, w2, w2, w2};
                xa[a] = pkfma4(w2v, r2, pkfma4(w1v, r1, w0v * r0));
            }
            // DFT8 (4 d-channels packed)
            v4f s0 = xa[0] + xa[4], dd0 = xa[0] - xa[4];
            v4f s1 = xa[1] + xa[5], dd1 = xa[1] - xa[5];
            v4f s2 = xa[2] + xa[6], dd2 = xa[2] - xa[6];
            v4f s3 = xa[3] + xa[7], dd3 = xa[3] - xa[7];
            v4f s02 = s0 + s2, s13 = s1 + s3;
            v4f F0 = s02 + s13, F4 = s02 - s13;
            v4f R2 = s0 - s2, I2 = s3 - s1;
            v4f u = RT2 * (dd1 - dd3), vt = RT2 * (dd1 + dd3);
            v4f R1 = dd0 + u, R3 = dd0 - u;
            v4f I1 = -dd2 - vt, I3 = dd2 - vt;
            // transpose to per-d spectra and write (8 x b128)
            float* ob = &Is[vv * 260 + d4 * 32];
            #pragma unroll
            for (int di = 0; di < 4; ++di) {
                *(v4f*)&ob[di * 8]     = (v4f){F0[di], F4[di], R1[di], I1[di]};
                *(v4f*)&ob[di * 8 + 4] = (v4f){R2[di], I2[di], R3[di], I3[di]};
            }
        }
        __syncthreads();  // Is ready

        // ---- spectral GEMM: lane's vertex x wave's 8 templates ----
        const float* ip0 = &Is[vL * 260];
        #pragma unroll 2
        for (int dl = 0; dl < 32; ++dl) {
            v4f pa = *(const v4f*)&ip0[dl * 8];
            v4f pb = *(const v4f*)&ip0[dl * 8 + 4];
            v2f x1 = pa.zw, x1n = {pa.w, -pa.z};
            v2f x2 = pb.xy, x2n = {pb.y, -pb.x};
            v2f x3 = pb.zw, x3n = {pb.w, -pb.z};
            // wave-uniform W slice: 64 contiguous floats -> s_load_dwordx16 x4
            const float* wb = &Wsg[(size_t)(((r * 32 + dl) * 4 + wvu) * 64)];
            #pragma unroll
            for (int tq = 0; tq < 8; ++tq) {
                v2f q01 = {wb[tq * 8 + 0], wb[tq * 8 + 1]};
                float q0z = wb[tq * 8 + 2], q0w = wb[tq * 8 + 3];
                float q1x = wb[tq * 8 + 4], q1y = wb[tq * 8 + 5];
                float q1z = wb[tq * 8 + 6], q1w = wb[tq * 8 + 7];
                A0[tq] = pkfma(pa.xy, q01, A0[tq]);
                A1[tq] = pkfmas(x1, q0z, A1[tq]);
                A1[tq] = pkfmas(x1n, q0w, A1[tq]);
                A2[tq] = pkfmas(x2, q1x, A2[tq]);
                A2[tq] = pkfmas(x2n, q1y, A2[tq]);
                A3[tq] = pkfmas(x3, q1z, A3[tq]);
                A3[tq] = pkfmas(x3n, q1w, A3[tq]);
            }
        }
    }

    // ---- IDFT8 + bias -> outk[tq][k]; per-wave norm partials ----
    float nrm[8];
    #pragma unroll
    for (int k = 0; k < 8; ++k) nrm[k] = 0.f;

    float outk[8][8];  // [tq][k]
    #pragma unroll
    for (int tq = 0; tq < 8; ++tq) {
        float bb = bias[wvu * 8 + tq];
        float C0 = A0[tq].x, C4 = A0[tq].y;
        float R1 = A1[tq].x, I1 = A1[tq].y;
        float R2 = A2[tq].x, I2 = A2[tq].y;
        float R3 = A3[tq].x, I3 = A3[tq].y;
        float e = 0.125f * (C0 + C4), o = 0.125f * (C0 - C4);
        float p = 0.25f * (R1 + R3), q = 0.25f * R2, s = 0.25f * (I1 - I3);
        float a_ = 0.25f * RT2 * (R1 - R3);
        float b_ = 0.25f * RT2 * (I1 + I3);
        float c_ = 0.25f * I2;
        outk[tq][0] = e + p + q + bb;
        outk[tq][1] = o + a_ - b_ - c_ + bb;
        outk[tq][2] = e - s - q + bb;
        outk[tq][3] = o - a_ - b_ + c_ + bb;
        outk[tq][4] = e - p + q + bb;
        outk[tq][5] = o - a_ + b_ - c_ + bb;
        outk[tq][6] = e + s - q + bb;
        outk[tq][7] = o + a_ + b_ + c_ + bb;
        #pragma unroll
        for (int k = 0; k < 8; ++k)
            nrm[k] = fmaf(outk[tq][k], outk[tq][k], nrm[k]);
    }

    // ---- cross-wave norm reduction (t is split across waves) ----
    {
        float* nb = &NrmS[(wvu * 64 + vL) * 8];
        *(v4f*)&nb[0] = (v4f){nrm[0], nrm[1], nrm[2], nrm[3]};
        *(v4f*)&nb[4] = (v4f){nrm[4], nrm[5], nrm[6], nrm[7]};
    }
    __syncthreads();
    v4f t0 = {0.f, 0.f, 0.f, 0.f}, t1 = {0.f, 0.f, 0.f, 0.f};
    #pragma unroll
    for (int w = 0; w < 4; ++w) {
        const float* nb = &NrmS[(w * 64 + vL) * 8];
        t0 += *(const v4f*)&nb[0];
        t1 += *(const v4f*)&nb[4];
    }
    float tot[8] = {t0.x, t0.y, t0.z, t0.w, t1.x, t1.y, t1.z, t1.w};
    // argmax over squared norms (sqrt is monotone; strict > keeps first max)
    int bk = 0;
    float best = tot[0];
    #pragma unroll
    for (int k = 1; k < 8; ++k) {
        if (tot[k] > best) { best = tot[k]; bk = k; }
    }

    // ---- select winning rotation, store, fused BN stats ----
    float selv[8];
    #pragma unroll
    for (int tq = 0; tq < 8; ++tq) {
        float sv = outk[tq][0];
        #pragma unroll
        for (int k = 1; k < 8; ++k) sv = (bk == k) ? outk[tq][k] : sv;
        selv[tq] = sv;
    }
    if (v < N) {
        float* o = s_out + (size_t)v * 32 + wvu * 8;
        *(v4f*)&o[0] = (v4f){selv[0], selv[1], selv[2], selv[3]};
        *(v4f*)&o[4] = (v4f){selv[4], selv[5], selv[6], selv[7]};
    }

    float sa[8], sb[8];
    #pragma unroll
    for (int tq = 0; tq < 8; ++tq) {
        float x = (v < N) ? selv[tq] : 0.f;
        sa[tq] = x;
        sb[tq] = x * x;
    }
    #pragma unroll
    for (int off = 1; off < 64; off <<= 1) {
        #pragma unroll
        for (int tq = 0; tq < 8; ++tq) {
            sa[tq] += __shfl_xor(sa[tq], off);
            sb[tq] += __shfl_xor(sb[tq], off);
        }
    }
    if (lane == 0) {
        #pragma unroll
        for (int tq = 0; tq < 8; ++tq) {
            atomicAdd(&sums[wvu * 8 + tq], (double)sa[tq]);
            atomicAdd(&sumsq[wvu * 8 + tq], (double)sb[tq]);
        }
    }
}

// ---------------------------------------------------------------------------
// Finalize BN: scale = gamma * rsqrt(var + eps), shift = beta - mu*scale
// ---------------------------------------------------------------------------
__global__ void finalize_kernel(const double* __restrict__ sums,
                                const double* __restrict__ sumsq,
                                const float* __restrict__ gamma,
                                const float* __restrict__ beta,
                                float* __restrict__ scale,
                                float* __restrict__ shift, int n) {
    int t = threadIdx.x;
    if (t < 32) {
        double mu = sums[t] / (double)n;
        double var = sumsq[t] / (double)n - mu * mu;
        double sc = (double)gamma[t] / sqrt(var + 1e-3);
        scale[t] = (float)sc;
        shift[t] = (float)((double)beta[t] - mu * sc);
    }
}

// ---------------------------------------------------------------------------
// sig2 = relu(scale*s + shift)   (branch 1 epilogue -> conv2 input)
// ---------------------------------------------------------------------------
__global__ void affine_relu_kernel(const float* __restrict__ s,
                                   const float* __restrict__ scale,
                                   const float* __restrict__ shift,
                                   float* __restrict__ o, int n4) {
    int e = blockIdx.x * blockDim.x + threadIdx.x;
    if (e >= n4) return;
    int t0 = (e & 7) * 4;
    float4 x = ((const float4*)s)[e];
    float4 y;
    y.x = fmaxf(fmaf(scale[t0 + 0], x.x, shift[t0 + 0]), 0.f);
    y.y = fmaxf(fmaf(scale[t0 + 1], x.y, shift[t0 + 1]), 0.f);
    y.z = fmaxf(fmaf(scale[t0 + 2], x.z, shift[t0 + 2]), 0.f);
    y.w = fmaxf(fmaf(scale[t0 + 3], x.w, shift[t0 + 3]), 0.f);
    ((float4*)o)[e] = y;
}

// ---------------------------------------------------------------------------
// out = relu(scale*s + shift + signal)   (final residual epilogue)
// ---------------------------------------------------------------------------
__global__ void final_kernel(const float* __restrict__ s,
                             const float* __restrict__ scale,
                             const float* __restrict__ shift,
                             const float* __restrict__ sig,
                             float* __restrict__ o, int n4) {
    int e = blockIdx.x * blockDim.x + threadIdx.x;
    if (e >= n4) return;
    int t0 = (e & 7) * 4;
    float4 x = ((const float4*)s)[e];
    float4 z = ((const float4*)sig)[e];
    float4 y;
    y.x = fmaxf(fmaf(scale[t0 + 0], x.x, shift[t0 + 0]) + z.x, 0.f);
    y.y = fmaxf(fmaf(scale[t0 + 1], x.y, shift[t0 + 1]) + z.y, 0.f);
    y.z = fmaxf(fmaf(scale[t0 + 2], x.z, shift[t0 + 2]) + z.z, 0.f);
    y.w = fmaxf(fmaf(scale[t0 + 3], x.w, shift[t0 + 3]) + z.w, 0.f);
    ((float4*)o)[e] = y;
}

// ---------------------------------------------------------------------------
extern "C" void kernel_launch(void* const* d_in, const int* in_sizes, int n_in,
                              void* d_out, int out_size, void* d_ws, size_t ws_size,
                              hipStream_t stream) {
    const float* signal = (const float*)d_in[0];
    const int* bc_idx   = (const int*)d_in[1];
    const float* bc_w   = (const float*)d_in[2];
    const float* W1     = (const float*)d_in[3];
    const float* b1     = (const float*)d_in[4];
    const float* g1     = (const float*)d_in[5];
    const float* be1    = (const float*)d_in[6];
    const float* W2     = (const float*)d_in[7];
    const float* b2     = (const float*)d_in[8];
    const float* g2     = (const float*)d_in[9];
    const float* be2    = (const float*)d_in[10];
    float* out = (float*)d_out;

    const int N = in_sizes[0] / 32;  // 80000

    char* ws = (char*)d_ws;
    double* sums1  = (double*)ws;         // 32
    double* sumsq1 = sums1 + 32;
    double* sums2  = sums1 + 64;
    double* sumsq2 = sums1 + 96;
    float* scale1 = (float*)(ws + 1024);
    float* shift1 = scale1 + 32;
    float* scale2 = scale1 + 64;
    float* shift2 = scale1 + 96;
    float* Ws1 = (float*)(ws + 4096);                 // 40960 floats = 160 KB
    float* Ws2 = Ws1 + RR * DD * TT * 8;
    float* s1  = Ws2 + RR * DD * TT * 8;
    float* sg2 = s1 + (size_t)N * 32;
    float* s2  = sg2 + (size_t)N * 32;

    int nBlocks = (N + 63) / 64;               // 1250

    // zero stats + both W spectra in one launch
    prep_kernel<<<40, 256, 0, stream>>>(W1, W2, Ws1, Ws2, (double*)ws, (float*)(ws + 1024));

    // ---- branch 1: fused gather+DFT+spectral-conv+pool+stats ----
    fused_conv_kernel<<<nBlocks, 256, 0, stream>>>(signal, bc_idx, bc_w, Ws1, b1, s1,
                                                   sums1, sumsq1, N);
    finalize_kernel<<<1, 32, 0, stream>>>(sums1, sumsq1, g1, be1, scale1, shift1, N);
    affine_relu_kernel<<<(N * 8 + 255) / 256, 256, 0, stream>>>(s1, scale1, shift1, sg2, N * 8);

    // ---- branch 2 ----
    fused_conv_kernel<<<nBlocks, 256, 0, stream>>>(sg2, bc_idx, bc_w, Ws2, b2, s2,
                                                   sums2, sumsq2, N);
    finalize_kernel<<<1, 32, 0, stream>>>(sums2, sumsq2, g2, be2, scale2, shift2, N);

    // ---- residual + relu ----
    final_kernel<<<(N * 8 + 255) / 256, 256, 0, stream>>>(s2, scale2, shift2, signal, out, N * 8);
}

// Round 6
// 733.145 us; speedup vs baseline: 1.4358x; 1.4358x over previous
//
#include <hip/hip_runtime.h>
#include <math.h>

// Problem constants (N=80000, Rr=5, A=8, D=32, T=32, K=8 rotations, ROT_DELTA=1)
#define RR 5
#define AA 8
#define DD 32
#define TT 32
#define KK 8

#define RT2 0.70710678118654752f

typedef float v2f __attribute__((ext_vector_type(2)));
typedef float v4f __attribute__((ext_vector_type(4)));

static __device__ __forceinline__ v2f pkfma(v2f a, v2f b, v2f c) {
#if __has_builtin(__builtin_elementwise_fma)
    return __builtin_elementwise_fma(a, b, c);
#else
    v2f r; r.x = fmaf(a.x, b.x, c.x); r.y = fmaf(a.y, b.y, c.y); return r;
#endif
}
static __device__ __forceinline__ v4f pkfma4(v4f a, v4f b, v4f c) {
#if __has_builtin(__builtin_elementwise_fma)
    return __builtin_elementwise_fma(a, b, c);
#else
    v4f r;
    r.x = fmaf(a.x, b.x, c.x); r.y = fmaf(a.y, b.y, c.y);
    r.z = fmaf(a.z, b.z, c.z); r.w = fmaf(a.w, b.w, c.w);
    return r;
#endif
}

// ---------------------------------------------------------------------------
// prep (round-1 verbatim, passed): zero stats + W spectral precompute ->
// Ws[(r*32+d)*256 + t*8 + f], f-pack = {F0,F4,R1,I1,R2,I2,R3,I3}.
// grid = 40 blocks: 0..19 -> W1, 20..39 -> W2. One thread per (t,r,d).
// ---------------------------------------------------------------------------
__global__ void prep_kernel(const float* __restrict__ W1, const float* __restrict__ W2,
                            float* __restrict__ Ws1, float* __restrict__ Ws2,
                            double* __restrict__ dz, float* __restrict__ fz) {
    int b = blockIdx.x;
    int tid = threadIdx.x;
    if (b == 0 && tid < 128) { dz[tid] = 0.0; fz[tid] = 0.f; }
    int which = (b >= 20) ? 1 : 0;
    const float* __restrict__ W = which ? W2 : W1;
    float* __restrict__ Ws = which ? Ws2 : Ws1;
    int idx = (b - which * 20) * 256 + tid;
    if (idx >= TT * RR * DD) return;
    int d = idx & 31;
    int tr = idx >> 5;      // t*5+r
    int t = tr / 5;
    int r = tr - t * 5;
    float xa[8];
    #pragma unroll
    for (int a = 0; a < 8; ++a) xa[a] = W[(tr * 8 + a) * 32 + d];
    float s0 = xa[0] + xa[4], d0 = xa[0] - xa[4];
    float s1 = xa[1] + xa[5], d1 = xa[1] - xa[5];
    float s2 = xa[2] + xa[6], d2 = xa[2] - xa[6];
    float s3 = xa[3] + xa[7], d3 = xa[3] - xa[7];
    float s02 = s0 + s2, s13 = s1 + s3;
    float F0 = s02 + s13, F4 = s02 - s13;
    float R2 = s0 - s2, I2 = s3 - s1;
    float u = RT2 * (d1 - d3), v = RT2 * (d1 + d3);
    float R1 = d0 + u, R3 = d0 - u;
    float I1 = -d2 - v, I3 = d2 - v;
    float* o = &Ws[(size_t)((r * 32 + d) * 256 + t * 8)];
    o[0] = F0; o[1] = F4; o[2] = R1; o[3] = I1;
    o[4] = R2; o[5] = I2; o[6] = R3; o[7] = I3;
}

// ---------------------------------------------------------------------------
// Fused kernel: gather + interp + DFT8 + spectral GEMM (fp32 VALU) + IDFT8 +
// bias + angular max pool + fused BN stats.
//
// Retile vs the 288us round-1 version: lane = vg(2b: 4 vertices) x tg(3b:
// 4 consecutive t) x dh(1b: d-half). Per dl: 8+8 b128 feed 224 MACs ->
// 1.0 b128 per 16-MAC unit (vs 1.5) => GEMM LDS instrs 384->256 /wave/r.
// W staged in 36-float tg-tiles (tg stride 144B -> 8 disjoint 4-bank spans,
// conflict-free). Is +16B swizzle on upper d-half keeps reads 2-way (free).
// Wave wv owns vertices [wv*16,wv*16+16) -> pooling stays wave-local
// (shfl over tg bits + one dh exchange).
// ---------------------------------------------------------------------------
__global__ __launch_bounds__(256, 2)
void fused_conv_kernel(const float* __restrict__ sig,
                       const int* __restrict__ bc_idx,
                       const float* __restrict__ bc_w,
                       const float* __restrict__ Wsg,
                       const float* __restrict__ bias,
                       float* __restrict__ s_out,
                       double* __restrict__ sums,
                       double* __restrict__ sumsq,
                       int N) {
    __shared__ float Is[64 * 260];   // 66560 B spectral interp, stride 260
    __shared__ float Wl[2304];       // 9216 B: 8 d-rows x 8 tg-tiles x 36

    int tid = threadIdx.x;
    int vBase = blockIdx.x * 64;
    int lane = tid & 63;
    int wv = tid >> 6;

    // GEMM lane roles
    int vg = lane & 3;               // 4 vertex-groups of 4
    int tg = (lane >> 2) & 7;        // 8 t-groups of 4 consecutive t
    int dh = lane >> 5;              // d-half: dl in [dh*16, dh*16+16)
    int vbL = wv * 16 + vg * 4;      // local vertex base (4 vertices)

    // gather-phase lane roles (v4f granularity, 8 lanes per vertex row)
    int d4 = tid & 7;                // floats 4*d4 .. 4*d4+3
    int g = tid >> 3;                // 0..31

    // accumulators per (vv 0..3, j 0..3), t = tg*4+j:
    // A0=(C0,C4) A1=(R1,I1) A2=(R2,I2) A3=(R3,I3); each lane sums its d-half
    v2f A0[4][4], A1[4][4], A2[4][4], A3[4][4];
    #pragma unroll
    for (int vv = 0; vv < 4; ++vv)
        #pragma unroll
        for (int j = 0; j < 4; ++j) {
            A0[vv][j] = (v2f){0.f, 0.f}; A1[vv][j] = (v2f){0.f, 0.f};
            A2[vv][j] = (v2f){0.f, 0.f}; A3[vv][j] = (v2f){0.f, 0.f};
        }

    for (int r = 0; r < RR; ++r) {
        __syncthreads();  // previous r's GEMM done with Is

        // ---- gather + interp + forward DFT8 -> Is ----
        #pragma unroll
        for (int vv0 = 0; vv0 < 2; ++vv0) {
            int vv = g + vv0 * 32;           // 0..63
            int vgl = vBase + vv;
            int vgc = (vgl < N) ? vgl : (N - 1);
            int base = vgc * 120 + r * 24;   // 16B-aligned
            int idxv[24]; float wbc[24];
            const int4* ib = (const int4*)(bc_idx + base);
            const float4* fb = (const float4*)(bc_w + base);
            #pragma unroll
            for (int q = 0; q < 6; ++q) {
                *(int4*)&idxv[q * 4] = ib[q];
                *(float4*)&wbc[q * 4] = fb[q];
            }
            v4f xa[8];
            #pragma unroll
            for (int a = 0; a < 8; ++a) {
                int i0 = idxv[a * 3 + 0];
                int i1 = idxv[a * 3 + 1];
                int i2 = idxv[a * 3 + 2];
                v4f r0 = *(const v4f*)&sig[(size_t)i0 * 32 + 4 * d4];
                v4f r1 = *(const v4f*)&sig[(size_t)i1 * 32 + 4 * d4];
                v4f r2 = *(const v4f*)&sig[(size_t)i2 * 32 + 4 * d4];
                float w0 = wbc[a * 3 + 0];
                float w1 = wbc[a * 3 + 1];
                float w2 = wbc[a * 3 + 2];
                v4f w0v = (v4f){w0, w0, w0, w0};
                v4f w1v = (v4f){w1, w1, w1, w1};
                v4f w2v = (v4f){w2, w2, w2, w2};
                xa[a] = pkfma4(w2v, r2, pkfma4(w1v, r1, w0v * r0));
            }
            // DFT8 (4 d-channels packed)
            v4f s0 = xa[0] + xa[4], dd0 = xa[0] - xa[4];
            v4f s1 = xa[1] + xa[5], dd1 = xa[1] - xa[5];
            v4f s2 = xa[2] + xa[6], dd2 = xa[2] - xa[6];
            v4f s3 = xa[3] + xa[7], dd3 = xa[3] - xa[7];
            v4f s02 = s0 + s2, s13 = s1 + s3;
            v4f F0 = s02 + s13, F4 = s02 - s13;
            v4f R2 = s0 - s2, I2 = s3 - s1;
            v4f u = RT2 * (dd1 - dd3), vt_ = RT2 * (dd1 + dd3);
            v4f R1 = dd0 + u, R3 = dd0 - u;
            v4f I1 = -dd2 - vt_, I3 = dd2 - vt_;
            // per-d spectra; +4-float swizzle for upper d-half (bank spread)
            float* ob = &Is[vv * 260 + d4 * 32 + (d4 >> 2) * 4];
            #pragma unroll
            for (int di = 0; di < 4; ++di) {
                *(v4f*)&ob[di * 8]     = (v4f){F0[di], F4[di], R1[di], I1[di]};
                *(v4f*)&ob[di * 8 + 4] = (v4f){R2[di], I2[di], R3[di], I3[di]};
            }
        }

        // ---- 4 W stages of 8 d-rows each ({ws*4..+3} U {16+ws*4..+3}) ----
        for (int ws = 0; ws < 4; ++ws) {
            __syncthreads();  // ws=0: gather visible; ws>0: prev GEMM done with Wl
            {
                // stage into padded tg-tiles: Wl[row*288 + tg*36 + j*8 + f]
                int row = tid >> 5;              // 0..7
                int rem = tid & 31;
                int stg = rem >> 2;              // 0..7
                int sjj = rem & 3;               // 0..3
                int d = (row < 4) ? (ws * 4 + row) : (12 + ws * 4 + row);
                const float* src = &Wsg[(size_t)((r * 32 + d) * 256 + (stg * 4 + sjj) * 8)];
                float* dst = &Wl[row * 288 + stg * 36 + sjj * 8];
                v4f a = *(const v4f*)&src[0];
                v4f b = *(const v4f*)&src[4];
                *(v4f*)&dst[0] = a;
                *(v4f*)&dst[4] = b;
            }
            __syncthreads();  // Wl visible

            #pragma unroll
            for (int dli = 0; dli < 4; ++dli) {
                int dgl = dh * 16 + ws * 4 + dli;          // global d
                int icol = dgl * 8 + dh * 4;               // swizzled Is col
                const float* wr = &Wl[(dh * 4 + dli) * 288 + tg * 36];
                v4f q0[4], q1[4];
                #pragma unroll
                for (int j = 0; j < 4; ++j) {
                    q0[j] = *(const v4f*)&wr[j * 8];
                    q1[j] = *(const v4f*)&wr[j * 8 + 4];
                }
                #pragma unroll
                for (int vv = 0; vv < 4; ++vv) {
                    const float* ip = &Is[(vbL + vv) * 260 + icol];
                    v4f pa = *(const v4f*)&ip[0];
                    v4f pb = *(const v4f*)&ip[4];
                    v2f x1 = pa.zw, x1n = {pa.w, -pa.z};
                    v2f x2 = pb.xy, x2n = {pb.y, -pb.x};
                    v2f x3 = pb.zw, x3n = {pb.w, -pb.z};
                    #pragma unroll
                    for (int j = 0; j < 4; ++j) {
                        v2f w2v = {q0[j].z, q0[j].z}, w3v = {q0[j].w, q0[j].w};
                        v2f w4v = {q1[j].x, q1[j].x}, w5v = {q1[j].y, q1[j].y};
                        v2f w6v = {q1[j].z, q1[j].z}, w7v = {q1[j].w, q1[j].w};
                        A0[vv][j] = pkfma(pa.xy, q0[j].xy, A0[vv][j]);
                        A1[vv][j] = pkfma(x1, w2v, A1[vv][j]);
                        A1[vv][j] = pkfma(x1n, w3v, A1[vv][j]);
                        A2[vv][j] = pkfma(x2, w4v, A2[vv][j]);
                        A2[vv][j] = pkfma(x2n, w5v, A2[vv][j]);
                        A3[vv][j] = pkfma(x3, w6v, A3[vv][j]);
                        A3[vv][j] = pkfma(x3n, w7v, A3[vv][j]);
                    }
                }
            }
        }
    }

    // ---- merge d-halves: acc += partner's (lane^32) partial ----
    #pragma unroll
    for (int vv = 0; vv < 4; ++vv)
        #pragma unroll
        for (int j = 0; j < 4; ++j) {
            A0[vv][j].x += __shfl_xor(A0[vv][j].x, 32);
            A0[vv][j].y += __shfl_xor(A0[vv][j].y, 32);
            A1[vv][j].x += __shfl_xor(A1[vv][j].x, 32);
            A1[vv][j].y += __shfl_xor(A1[vv][j].y, 32);
            A2[vv][j].x += __shfl_xor(A2[vv][j].x, 32);
            A2[vv][j].y += __shfl_xor(A2[vv][j].y, 32);
            A3[vv][j].x += __shfl_xor(A3[vv][j].x, 32);
            A3[vv][j].y += __shfl_xor(A3[vv][j].y, 32);
        }

    // ---- IDFT8 + bias; dh computes its 4-k half: k = dh*4 + kk ----
    float bj[4];
    #pragma unroll
    for (int j = 0; j < 4; ++j) bj[j] = bias[tg * 4 + j];

    float outL[4][4][4];  // [vv][kk][j]
    #pragma unroll
    for (int vv = 0; vv < 4; ++vv) {
        #pragma unroll
        for (int j = 0; j < 4; ++j) {
            float C0 = A0[vv][j].x, C4 = A0[vv][j].y;
            float R1 = A1[vv][j].x, I1 = A1[vv][j].y;
            float R2 = A2[vv][j].x, I2 = A2[vv][j].y;
            float R3 = A3[vv][j].x, I3 = A3[vv][j].y;
            float e = 0.125f * (C0 + C4), o = 0.125f * (C0 - C4);
            float p = 0.25f * (R1 + R3), q = 0.25f * R2, s = 0.25f * (I1 - I3);
            float a_ = 0.25f * RT2 * (R1 - R3);
            float b_ = 0.25f * RT2 * (I1 + I3);
            float c_ = 0.25f * I2;
            float bb = bj[j];
            float o0 = e + p + q + bb, o4 = e - p + q + bb;
            float o1 = o + a_ - b_ - c_ + bb, o5 = o - a_ + b_ - c_ + bb;
            float o2 = e - s - q + bb, o6 = e + s - q + bb;
            float o3 = o - a_ - b_ + c_ + bb, o7 = o + a_ + b_ + c_ + bb;
            outL[vv][0][j] = dh ? o4 : o0;
            outL[vv][1][j] = dh ? o5 : o1;
            outL[vv][2][j] = dh ? o6 : o2;
            outL[vv][3][j] = dh ? o7 : o3;
        }
    }

    // ---- norms: reduce over tg (bits 2..4); exchange across dh ----
    float nrm[4][4], pn[4][4];
    #pragma unroll
    for (int vv = 0; vv < 4; ++vv)
        #pragma unroll
        for (int kk = 0; kk < 4; ++kk) {
            float nl = 0.f;
            #pragma unroll
            for (int j = 0; j < 4; ++j)
                nl = fmaf(outL[vv][kk][j], outL[vv][kk][j], nl);
            nl += __shfl_xor(nl, 4);
            nl += __shfl_xor(nl, 8);
            nl += __shfl_xor(nl, 16);
            nrm[vv][kk] = nl;
            pn[vv][kk] = __shfl_xor(nl, 32);
        }

    float sa[4] = {0.f, 0.f, 0.f, 0.f};
    float sb[4] = {0.f, 0.f, 0.f, 0.f};

    #pragma unroll
    for (int vv = 0; vv < 4; ++vv) {
        // absolute-k norm vector (identical on both dh halves)
        float n8[8];
        #pragma unroll
        for (int kk = 0; kk < 4; ++kk) {
            float a = nrm[vv][kk], b = pn[vv][kk];
            n8[kk]     = dh ? b : a;
            n8[kk + 4] = dh ? a : b;
        }
        int bk = 0;
        float best = n8[0];
        #pragma unroll
        for (int k = 1; k < 8; ++k) {
            if (n8[k] > best) { best = n8[k]; bk = k; }
        }
        int winhere = ((bk >> 2) == dh);
        int bkk = bk & 3;
        float sv[4] = {0.f, 0.f, 0.f, 0.f};
        #pragma unroll
        for (int kk = 0; kk < 4; ++kk) {
            if (kk == bkk) {
                #pragma unroll
                for (int j = 0; j < 4; ++j) sv[j] = outL[vv][kk][j];
            }
        }
        #pragma unroll
        for (int j = 0; j < 4; ++j) {
            sv[j] = winhere ? sv[j] : 0.f;
            sv[j] += __shfl_xor(sv[j], 32);   // both halves now hold winner
        }
        int v = vBase + vbL + vv;
        if (dh == 0 && v < N) {
            *(v4f*)&s_out[(size_t)v * 32 + tg * 4] = (v4f){sv[0], sv[1], sv[2], sv[3]};
        }
        float msk = (v < N) ? 1.f : 0.f;
        #pragma unroll
        for (int j = 0; j < 4; ++j) {
            float x = msk * sv[j];
            sa[j] += x;
            sb[j] = fmaf(x, x, sb[j]);
        }
    }

    // ---- fused BN stats: reduce over vg (bits 0..1), stage via Wl ----
    #pragma unroll
    for (int j = 0; j < 4; ++j) {
        sa[j] += __shfl_xor(sa[j], 1);
        sb[j] += __shfl_xor(sb[j], 1);
        sa[j] += __shfl_xor(sa[j], 2);
        sb[j] += __shfl_xor(sb[j], 2);
    }
    __syncthreads();  // all waves done reading Wl -> reuse as stats scratch
    if (dh == 0 && vg == 0) {
        float* wst = (float*)Wl;  // [wv][t][2]
        #pragma unroll
        for (int j = 0; j < 4; ++j) {
            int t = tg * 4 + j;
            wst[(wv * 32 + t) * 2 + 0] = sa[j];
            wst[(wv * 32 + t) * 2 + 1] = sb[j];
        }
    }
    __syncthreads();
    if (tid < 64) {
        const float* wst = (const float*)Wl;
        int t = tid >> 1, c = tid & 1;
        float s = wst[t * 2 + c] + wst[64 + t * 2 + c] +
                  wst[128 + t * 2 + c] + wst[192 + t * 2 + c];
        if (c == 0) atomicAdd(&sums[t], (double)s);
        else        atomicAdd(&sumsq[t], (double)s);
    }
}

// ---------------------------------------------------------------------------
// Finalize BN: scale = gamma * rsqrt(var + eps), shift = beta - mu*scale
// ---------------------------------------------------------------------------
__global__ void finalize_kernel(const double* __restrict__ sums,
                                const double* __restrict__ sumsq,
                                const float* __restrict__ gamma,
                                const float* __restrict__ beta,
                                float* __restrict__ scale,
                                float* __restrict__ shift, int n) {
    int t = threadIdx.x;
    if (t < 32) {
        double mu = sums[t] / (double)n;
        double var = sumsq[t] / (double)n - mu * mu;
        double sc = (double)gamma[t] / sqrt(var + 1e-3);
        scale[t] = (float)sc;
        shift[t] = (float)((double)beta[t] - mu * sc);
    }
}

// ---------------------------------------------------------------------------
// sig2 = relu(scale*s + shift)   (branch 1 epilogue -> conv2 input)
// ---------------------------------------------------------------------------
__global__ void affine_relu_kernel(const float* __restrict__ s,
                                   const float* __restrict__ scale,
                                   const float* __restrict__ shift,
                                   float* __restrict__ o, int n4) {
    int e = blockIdx.x * blockDim.x + threadIdx.x;
    if (e >= n4) return;
    int t0 = (e & 7) * 4;
    float4 x = ((const float4*)s)[e];
    float4 y;
    y.x = fmaxf(fmaf(scale[t0 + 0], x.x, shift[t0 + 0]), 0.f);
    y.y = fmaxf(fmaf(scale[t0 + 1], x.y, shift[t0 + 1]), 0.f);
    y.z = fmaxf(fmaf(scale[t0 + 2], x.z, shift[t0 + 2]), 0.f);
    y.w = fmaxf(fmaf(scale[t0 + 3], x.w, shift[t0 + 3]), 0.f);
    ((float4*)o)[e] = y;
}

// ---------------------------------------------------------------------------
// out = relu(scale*s + shift + signal)   (final residual epilogue)
// ---------------------------------------------------------------------------
__global__ void final_kernel(const float* __restrict__ s,
                             const float* __restrict__ scale,
                             const float* __restrict__ shift,
                             const float* __restrict__ sig,
                             float* __restrict__ o, int n4) {
    int e = blockIdx.x * blockDim.x + threadIdx.x;
    if (e >= n4) return;
    int t0 = (e & 7) * 4;
    float4 x = ((const float4*)s)[e];
    float4 z = ((const float4*)sig)[e];
    float4 y;
    y.x = fmaxf(fmaf(scale[t0 + 0], x.x, shift[t0 + 0]) + z.x, 0.f);
    y.y = fmaxf(fmaf(scale[t0 + 1], x.y, shift[t0 + 1]) + z.y, 0.f);
    y.z = fmaxf(fmaf(scale[t0 + 2], x.z, shift[t0 + 2]) + z.z, 0.f);
    y.w = fmaxf(fmaf(scale[t0 + 3], x.w, shift[t0 + 3]) + z.w, 0.f);
    ((float4*)o)[e] = y;
}

// ---------------------------------------------------------------------------
extern "C" void kernel_launch(void* const* d_in, const int* in_sizes, int n_in,
                              void* d_out, int out_size, void* d_ws, size_t ws_size,
                              hipStream_t stream) {
    const float* signal = (const float*)d_in[0];
    const int* bc_idx   = (const int*)d_in[1];
    const float* bc_w   = (const float*)d_in[2];
    const float* W1     = (const float*)d_in[3];
    const float* b1     = (const float*)d_in[4];
    const float* g1     = (const float*)d_in[5];
    const float* be1    = (const float*)d_in[6];
    const float* W2     = (const float*)d_in[7];
    const float* b2     = (const float*)d_in[8];
    const float* g2     = (const float*)d_in[9];
    const float* be2    = (const float*)d_in[10];
    float* out = (float*)d_out;

    const int N = in_sizes[0] / 32;  // 80000

    char* ws = (char*)d_ws;
    double* sums1  = (double*)ws;         // 32
    double* sumsq1 = sums1 + 32;
    double* sums2  = sums1 + 64;
    double* sumsq2 = sums1 + 96;
    float* scale1 = (float*)(ws + 1024);
    float* shift1 = scale1 + 32;
    float* scale2 = scale1 + 64;
    float* shift2 = scale1 + 96;
    float* Ws1 = (float*)(ws + 4096);                 // 40960 floats = 160 KB
    float* Ws2 = Ws1 + RR * DD * TT * 8;
    float* s1  = Ws2 + RR * DD * TT * 8;
    float* sg2 = s1 + (size_t)N * 32;
    float* s2  = sg2 + (size_t)N * 32;

    int nBlocks = (N + 63) / 64;               // 1250

    // zero stats + both W spectra in one launch
    prep_kernel<<<40, 256, 0, stream>>>(W1, W2, Ws1, Ws2, (double*)ws, (float*)(ws + 1024));

    // ---- branch 1: fused gather+DFT+spectral-conv+pool+stats ----
    fused_conv_kernel<<<nBlocks, 256, 0, stream>>>(signal, bc_idx, bc_w, Ws1, b1, s1,
                                                   sums1, sumsq1, N);
    finalize_kernel<<<1, 32, 0, stream>>>(sums1, sumsq1, g1, be1, scale1, shift1, N);
    affine_relu_kernel<<<(N * 8 + 255) / 256, 256, 0, stream>>>(s1, scale1, shift1, sg2, N * 8);

    // ---- branch 2 ----
    fused_conv_kernel<<<nBlocks, 256, 0, stream>>>(sg2, bc_idx, bc_w, Ws2, b2, s2,
                                                   sums2, sumsq2, N);
    finalize_kernel<<<1, 32, 0, stream>>>(sums2, sumsq2, g2, be2, scale2, shift2, N);

    // ---- residual + relu ----
    final_kernel<<<(N * 8 + 255) / 256, 256, 0, stream>>>(s2, scale2, shift2, signal, out, N * 8);
}

// Round 7
// 678.425 us; speedup vs baseline: 1.5517x; 1.0807x over previous
//
#include <hip/hip_runtime.h>
#include <math.h>

// Problem constants (N=80000, Rr=5, A=8, D=32, T=32, K=8 rotations, ROT_DELTA=1)
#define RR 5
#define AA 8
#define DD 32
#define TT 32
#define KK 8

#define RT2 0.70710678118654752f

typedef float v2f __attribute__((ext_vector_type(2)));
typedef float v4f __attribute__((ext_vector_type(4)));

static __device__ __forceinline__ v2f pkfma(v2f a, v2f b, v2f c) {
#if __has_builtin(__builtin_elementwise_fma)
    return __builtin_elementwise_fma(a, b, c);
#else
    v2f r; r.x = fmaf(a.x, b.x, c.x); r.y = fmaf(a.y, b.y, c.y); return r;
#endif
}
static __device__ __forceinline__ v4f pkfma4(v4f a, v4f b, v4f c) {
#if __has_builtin(__builtin_elementwise_fma)
    return __builtin_elementwise_fma(a, b, c);
#else
    v4f r;
    r.x = fmaf(a.x, b.x, c.x); r.y = fmaf(a.y, b.y, c.y);
    r.z = fmaf(a.z, b.z, c.z); r.w = fmaf(a.w, b.w, c.w);
    return r;
#endif
}

// ---------------------------------------------------------------------------
// prep (passed, verbatim): zero stats + W spectral precompute ->
// Ws[(r*32+d)*256 + t*8 + f], f-pack = {F0,F4,R1,I1,R2,I2,R3,I3}.
// grid = 40 blocks: 0..19 -> W1, 20..39 -> W2. One thread per (t,r,d).
// ---------------------------------------------------------------------------
__global__ void prep_kernel(const float* __restrict__ W1, const float* __restrict__ W2,
                            float* __restrict__ Ws1, float* __restrict__ Ws2,
                            double* __restrict__ dz, float* __restrict__ fz) {
    int b = blockIdx.x;
    int tid = threadIdx.x;
    if (b == 0 && tid < 128) { dz[tid] = 0.0; fz[tid] = 0.f; }
    int which = (b >= 20) ? 1 : 0;
    const float* __restrict__ W = which ? W2 : W1;
    float* __restrict__ Ws = which ? Ws2 : Ws1;
    int idx = (b - which * 20) * 256 + tid;
    if (idx >= TT * RR * DD) return;
    int d = idx & 31;
    int tr = idx >> 5;      // t*5+r
    int t = tr / 5;
    int r = tr - t * 5;
    float xa[8];
    #pragma unroll
    for (int a = 0; a < 8; ++a) xa[a] = W[(tr * 8 + a) * 32 + d];
    float s0 = xa[0] + xa[4], d0 = xa[0] - xa[4];
    float s1 = xa[1] + xa[5], d1 = xa[1] - xa[5];
    float s2 = xa[2] + xa[6], d2 = xa[2] - xa[6];
    float s3 = xa[3] + xa[7], d3 = xa[3] - xa[7];
    float s02 = s0 + s2, s13 = s1 + s3;
    float F0 = s02 + s13, F4 = s02 - s13;
    float R2 = s0 - s2, I2 = s3 - s1;
    float u = RT2 * (d1 - d3), v = RT2 * (d1 + d3);
    float R1 = d0 + u, R3 = d0 - u;
    float I1 = -d2 - v, I3 = d2 - v;
    float* o = &Ws[(size_t)((r * 32 + d) * 256 + t * 8)];
    o[0] = F0; o[1] = F4; o[2] = R1; o[3] = I1;
    o[4] = R2; o[5] = I2; o[6] = R3; o[7] = I3;
}

// ---------------------------------------------------------------------------
// Fused kernel: gather + interp + DFT8 + spectral GEMM (fp32 VALU) + IDFT8 +
// bias + angular max pool + fused BN stats.
//
// WAVE-AUTONOMOUS: wave wv owns vertices [wv*16, wv*16+16) for BOTH the
// gather (8 lanes/vertex, 2 passes) and the GEMM (lane tile 2v x 4t, pair
// (v, v+8) -- the empirically-best 288us shape). W is read straight from
// global (prep-packed, L2-resident) instead of cooperative LDS staging.
// => ZERO __syncthreads in the r-loop; the 8 resident waves/CU desync so
// one wave's gather VMEM latency hides under other waves' GEMM VALU bursts
// (round-6 falsified the LDS-issue theory: fewer LDS instrs+conflicts was
// SLOWER; the loss is lockstep barrier stalls at 2 waves/SIMD occupancy).
// Is write/read col swizzle (d>>4)*4: write conflicts 8-way -> 4-way.
// DS ops complete in order per wave; phase fences are belt-and-braces.
// ---------------------------------------------------------------------------
__global__ __launch_bounds__(256, 2)
void fused_conv_kernel(const float* __restrict__ sig,
                       const int* __restrict__ bc_idx,
                       const float* __restrict__ bc_w,
                       const float* __restrict__ Wsg,
                       const float* __restrict__ bias,
                       float* __restrict__ s_out,
                       double* __restrict__ sums,
                       double* __restrict__ sumsq,
                       int N) {
    __shared__ float Is[64 * 260];   // 66560 B spectral interp, stride 260
    __shared__ float StS[256];       // 1 KB stats scratch (epilogue only)

    int tid = threadIdx.x;
    int vBase = blockIdx.x * 64;
    int lane = tid & 63;
    int wv = tid >> 6;

    // GEMM lane roles: vg = vertex within wave-own 16, tg = t-group
    int vg = lane & 7;
    int tg = lane >> 3;              // 0..7
    int v0L = wv * 16 + vg;          // pair = (v0L, v0L+8)
    int v1L = v0L + 8;
    int v0 = vBase + v0L;
    int v1 = vBase + v1L;

    // gather-phase lane roles (wave-local): 8 lanes per vertex
    int d4 = lane & 7;               // floats 4*d4 .. 4*d4+3
    int g8 = lane >> 3;              // 0..7

    // spectral accumulators per (vv in {0,1}, j in 0..3):
    // A0=(C0,C4) A1=(R1,I1) A2=(R2,I2) A3=(R3,I3)
    v2f A0[2][4], A1[2][4], A2[2][4], A3[2][4];
    #pragma unroll
    for (int vv = 0; vv < 2; ++vv)
        #pragma unroll
        for (int j = 0; j < 4; ++j) {
            A0[vv][j] = (v2f){0.f, 0.f}; A1[vv][j] = (v2f){0.f, 0.f};
            A2[vv][j] = (v2f){0.f, 0.f}; A3[vv][j] = (v2f){0.f, 0.f};
        }

    for (int r = 0; r < RR; ++r) {
        // ---- gather + interp + forward DFT8 -> wave-own Is rows ----
        #pragma unroll
        for (int vv0 = 0; vv0 < 2; ++vv0) {
            int vvL = wv * 16 + vv0 * 8 + g8;   // wave-own local row
            int vgl = vBase + vvL;
            int vgc = (vgl < N) ? vgl : (N - 1);
            int base = vgc * 120 + r * 24;      // 16B-aligned
            int idxv[24]; float wbc[24];
            const int4* ib = (const int4*)(bc_idx + base);
            const float4* fb = (const float4*)(bc_w + base);
            #pragma unroll
            for (int q = 0; q < 6; ++q) {
                *(int4*)&idxv[q * 4] = ib[q];
                *(float4*)&wbc[q * 4] = fb[q];
            }
            v4f xa[8];
            #pragma unroll
            for (int a = 0; a < 8; ++a) {
                int i0 = idxv[a * 3 + 0];
                int i1 = idxv[a * 3 + 1];
                int i2 = idxv[a * 3 + 2];
                v4f r0 = *(const v4f*)&sig[(size_t)i0 * 32 + 4 * d4];
                v4f r1 = *(const v4f*)&sig[(size_t)i1 * 32 + 4 * d4];
                v4f r2 = *(const v4f*)&sig[(size_t)i2 * 32 + 4 * d4];
                float w0 = wbc[a * 3 + 0];
                float w1 = wbc[a * 3 + 1];
                float w2 = wbc[a * 3 + 2];
                v4f w0v = (v4f){w0, w0, w0, w0};
                v4f w1v = (v4f){w1, w1, w1, w1};
                v4f w2v = (v4f){w2, w2, w2, w2};
                xa[a] = pkfma4(w2v, r2, pkfma4(w1v, r1, w0v * r0));
            }
            // DFT8 (4 d-channels packed)
            v4f s0 = xa[0] + xa[4], dd0 = xa[0] - xa[4];
            v4f s1 = xa[1] + xa[5], dd1 = xa[1] - xa[5];
            v4f s2 = xa[2] + xa[6], dd2 = xa[2] - xa[6];
            v4f s3 = xa[3] + xa[7], dd3 = xa[3] - xa[7];
            v4f s02 = s0 + s2, s13 = s1 + s3;
            v4f F0 = s02 + s13, F4 = s02 - s13;
            v4f R2 = s0 - s2, I2 = s3 - s1;
            v4f u = RT2 * (dd1 - dd3), vt_ = RT2 * (dd1 + dd3);
            v4f R1 = dd0 + u, R3 = dd0 - u;
            v4f I1 = -dd2 - vt_, I3 = dd2 - vt_;
            // per-d spectra; col swizzle (d>>4)*4 spreads write banks
            float* ob = &Is[vvL * 260 + d4 * 32 + (d4 >> 2) * 4];
            #pragma unroll
            for (int di = 0; di < 4; ++di) {
                *(v4f*)&ob[di * 8]     = (v4f){F0[di], F4[di], R1[di], I1[di]};
                *(v4f*)&ob[di * 8 + 4] = (v4f){R2[di], I2[di], R3[di], I3[di]};
            }
        }
        // same-wave LDS write->read: DS is in-order per wave; fence as insurance
        asm volatile("s_waitcnt lgkmcnt(0)" ::: "memory");
        __builtin_amdgcn_sched_barrier(0);

        // ---- spectral GEMM for this r: W streamed from global (L2) ----
        const float* wrb = &Wsg[(size_t)(r * 32) * 256];
        #pragma unroll 2
        for (int dl = 0; dl < 32; ++dl) {
            const float* ip = &Is[v0L * 260 + dl * 8 + (dl >> 4) * 4];
            v4f pa0 = *(const v4f*)&ip[0];
            v4f pb0 = *(const v4f*)&ip[4];
            v4f pa1 = *(const v4f*)&ip[2080];   // vertex v0L+8
            v4f pb1 = *(const v4f*)&ip[2084];
            v2f x1_0 = pa0.zw, x1n_0 = {pa0.w, -pa0.z};
            v2f x2_0 = pb0.xy, x2n_0 = {pb0.y, -pb0.x};
            v2f x3_0 = pb0.zw, x3n_0 = {pb0.w, -pb0.z};
            v2f x1_1 = pa1.zw, x1n_1 = {pa1.w, -pa1.z};
            v2f x2_1 = pb1.xy, x2n_1 = {pb1.y, -pb1.x};
            v2f x3_1 = pb1.zw, x3n_1 = {pb1.w, -pb1.z};
            const float* wrow = wrb + dl * 256;
            #pragma unroll
            for (int j = 0; j < 4; ++j) {
                v4f q0 = *(const v4f*)&wrow[(tg + 8 * j) * 8];
                v4f q1 = *(const v4f*)&wrow[(tg + 8 * j) * 8 + 4];
                v2f w2v = {q0.z, q0.z}, w3v = {q0.w, q0.w};
                v2f w4v = {q1.x, q1.x}, w5v = {q1.y, q1.y};
                v2f w6v = {q1.z, q1.z}, w7v = {q1.w, q1.w};
                // vv = 0
                A0[0][j] = pkfma(pa0.xy, q0.xy, A0[0][j]);
                A1[0][j] = pkfma(x1_0, w2v, A1[0][j]);
                A1[0][j] = pkfma(x1n_0, w3v, A1[0][j]);
                A2[0][j] = pkfma(x2_0, w4v, A2[0][j]);
                A2[0][j] = pkfma(x2n_0, w5v, A2[0][j]);
                A3[0][j] = pkfma(x3_0, w6v, A3[0][j]);
                A3[0][j] = pkfma(x3n_0, w7v, A3[0][j]);
                // vv = 1
                A0[1][j] = pkfma(pa1.xy, q0.xy, A0[1][j]);
                A1[1][j] = pkfma(x1_1, w2v, A1[1][j]);
                A1[1][j] = pkfma(x1n_1, w3v, A1[1][j]);
                A2[1][j] = pkfma(x2_1, w4v, A2[1][j]);
                A2[1][j] = pkfma(x2n_1, w5v, A2[1][j]);
                A3[1][j] = pkfma(x3_1, w6v, A3[1][j]);
                A3[1][j] = pkfma(x3n_1, w7v, A3[1][j]);
            }
        }
        // GEMM reads done before next gather overwrites (in-order DS); fence
        asm volatile("s_waitcnt lgkmcnt(0)" ::: "memory");
        __builtin_amdgcn_sched_barrier(0);
    }

    // ---- IDFT8 + bias per (vv, t) ----
    float bj[4];
    #pragma unroll
    for (int j = 0; j < 4; ++j) bj[j] = bias[tg + 8 * j];

    float outk[2][8][4];  // [vv][k][j]
    #pragma unroll
    for (int vv = 0; vv < 2; ++vv) {
        #pragma unroll
        for (int j = 0; j < 4; ++j) {
            float C0 = A0[vv][j].x, C4 = A0[vv][j].y;
            float R1 = A1[vv][j].x, I1 = A1[vv][j].y;
            float R2 = A2[vv][j].x, I2 = A2[vv][j].y;
            float R3 = A3[vv][j].x, I3 = A3[vv][j].y;
            float e = 0.125f * (C0 + C4), o = 0.125f * (C0 - C4);
            float p = 0.25f * (R1 + R3), q = 0.25f * R2, s = 0.25f * (I1 - I3);
            float a_ = 0.25f * RT2 * (R1 - R3);
            float b_ = 0.25f * RT2 * (I1 + I3);
            float c_ = 0.25f * I2;
            float bb = bj[j];
            outk[vv][0][j] = e + p + q + bb;
            outk[vv][1][j] = o + a_ - b_ - c_ + bb;
            outk[vv][2][j] = e - s - q + bb;
            outk[vv][3][j] = o - a_ - b_ + c_ + bb;
            outk[vv][4][j] = e - p + q + bb;
            outk[vv][5][j] = o - a_ + b_ - c_ + bb;
            outk[vv][6][j] = e + s - q + bb;
            outk[vv][7][j] = o + a_ + b_ + c_ + bb;
        }
    }

    // ---- norms: wave-local reduce over tg (lane bits 3..5) + select ----
    float sel[2][4];
    int vOutA[2]; vOutA[0] = v0; vOutA[1] = v1;
    #pragma unroll
    for (int vv = 0; vv < 2; ++vv) {
        float norms[8];
        #pragma unroll
        for (int k = 0; k < 8; ++k) {
            float nl = 0.f;
            #pragma unroll
            for (int j = 0; j < 4; ++j)
                nl = fmaf(outk[vv][k][j], outk[vv][k][j], nl);
            nl += __shfl_xor(nl, 8);
            nl += __shfl_xor(nl, 16);
            nl += __shfl_xor(nl, 32);
            norms[k] = nl;
        }
        float best = -1.f;
        int bk = 0;
        #pragma unroll
        for (int k = 0; k < 8; ++k) {
            float n = sqrtf(norms[k]);
            if (n > best) { best = n; bk = k; }
        }
        #pragma unroll
        for (int j = 0; j < 4; ++j) sel[vv][j] = 0.f;
        #pragma unroll
        for (int k = 0; k < 8; ++k) {
            if (k == bk) {
                #pragma unroll
                for (int j = 0; j < 4; ++j) sel[vv][j] = outk[vv][k][j];
            }
        }
        if (vOutA[vv] < N) {
            float* o = s_out + (size_t)vOutA[vv] * 32 + tg;
            o[0]  = sel[vv][0];
            o[8]  = sel[vv][1];
            o[16] = sel[vv][2];
            o[24] = sel[vv][3];
        }
    }

    // ---- fused BN stats: reduce over vg (bits 0..2), stage via StS ----
    float pa_[4], pb_[4];
    #pragma unroll
    for (int j = 0; j < 4; ++j) {
        float s0 = (v0 < N) ? sel[0][j] : 0.f;
        float s1 = (v1 < N) ? sel[1][j] : 0.f;
        pa_[j] = s0 + s1;
        pb_[j] = fmaf(s0, s0, s1 * s1);
    }
    #pragma unroll
    for (int j = 0; j < 4; ++j) {
        pa_[j] += __shfl_xor(pa_[j], 1);
        pb_[j] += __shfl_xor(pb_[j], 1);
        pa_[j] += __shfl_xor(pa_[j], 2);
        pb_[j] += __shfl_xor(pb_[j], 2);
        pa_[j] += __shfl_xor(pa_[j], 4);
        pb_[j] += __shfl_xor(pb_[j], 4);
    }
    __syncthreads();
    if (vg == 0) {
        #pragma unroll
        for (int j = 0; j < 4; ++j) {
            int t = tg + 8 * j;
            StS[(wv * 32 + t) * 2 + 0] = pa_[j];
            StS[(wv * 32 + t) * 2 + 1] = pb_[j];
        }
    }
    __syncthreads();
    if (tid < 64) {
        int t = tid >> 1, c = tid & 1;
        float s = StS[t * 2 + c] + StS[64 + t * 2 + c] +
                  StS[128 + t * 2 + c] + StS[192 + t * 2 + c];
        if (c == 0) atomicAdd(&sums[t], (double)s);
        else        atomicAdd(&sumsq[t], (double)s);
    }
}

// ---------------------------------------------------------------------------
// Finalize BN: scale = gamma * rsqrt(var + eps), shift = beta - mu*scale
// ---------------------------------------------------------------------------
__global__ void finalize_kernel(const double* __restrict__ sums,
                                const double* __restrict__ sumsq,
                                const float* __restrict__ gamma,
                                const float* __restrict__ beta,
                                float* __restrict__ scale,
                                float* __restrict__ shift, int n) {
    int t = threadIdx.x;
    if (t < 32) {
        double mu = sums[t] / (double)n;
        double var = sumsq[t] / (double)n - mu * mu;
        double sc = (double)gamma[t] / sqrt(var + 1e-3);
        scale[t] = (float)sc;
        shift[t] = (float)((double)beta[t] - mu * sc);
    }
}

// ---------------------------------------------------------------------------
// sig2 = relu(scale*s + shift)   (branch 1 epilogue -> conv2 input)
// ---------------------------------------------------------------------------
__global__ void affine_relu_kernel(const float* __restrict__ s,
                                   const float* __restrict__ scale,
                                   const float* __restrict__ shift,
                                   float* __restrict__ o, int n4) {
    int e = blockIdx.x * blockDim.x + threadIdx.x;
    if (e >= n4) return;
    int t0 = (e & 7) * 4;
    float4 x = ((const float4*)s)[e];
    float4 y;
    y.x = fmaxf(fmaf(scale[t0 + 0], x.x, shift[t0 + 0]), 0.f);
    y.y = fmaxf(fmaf(scale[t0 + 1], x.y, shift[t0 + 1]), 0.f);
    y.z = fmaxf(fmaf(scale[t0 + 2], x.z, shift[t0 + 2]), 0.f);
    y.w = fmaxf(fmaf(scale[t0 + 3], x.w, shift[t0 + 3]), 0.f);
    ((float4*)o)[e] = y;
}

// ---------------------------------------------------------------------------
// out = relu(scale*s + shift + signal)   (final residual epilogue)
// ---------------------------------------------------------------------------
__global__ void final_kernel(const float* __restrict__ s,
                             const float* __restrict__ scale,
                             const float* __restrict__ shift,
                             const float* __restrict__ sig,
                             float* __restrict__ o, int n4) {
    int e = blockIdx.x * blockDim.x + threadIdx.x;
    if (e >= n4) return;
    int t0 = (e & 7) * 4;
    float4 x = ((const float4*)s)[e];
    float4 z = ((const float4*)sig)[e];
    float4 y;
    y.x = fmaxf(fmaf(scale[t0 + 0], x.x, shift[t0 + 0]) + z.x, 0.f);
    y.y = fmaxf(fmaf(scale[t0 + 1], x.y, shift[t0 + 1]) + z.y, 0.f);
    y.z = fmaxf(fmaf(scale[t0 + 2], x.z, shift[t0 + 2]) + z.z, 0.f);
    y.w = fmaxf(fmaf(scale[t0 + 3], x.w, shift[t0 + 3]) + z.w, 0.f);
    ((float4*)o)[e] = y;
}

// ---------------------------------------------------------------------------
extern "C" void kernel_launch(void* const* d_in, const int* in_sizes, int n_in,
                              void* d_out, int out_size, void* d_ws, size_t ws_size,
                              hipStream_t stream) {
    const float* signal = (const float*)d_in[0];
    const int* bc_idx   = (const int*)d_in[1];
    const float* bc_w   = (const float*)d_in[2];
    const float* W1     = (const float*)d_in[3];
    const float* b1     = (const float*)d_in[4];
    const float* g1     = (const float*)d_in[5];
    const float* be1    = (const float*)d_in[6];
    const float* W2     = (const float*)d_in[7];
    const float* b2     = (const float*)d_in[8];
    const float* g2     = (const float*)d_in[9];
    const float* be2    = (const float*)d_in[10];
    float* out = (float*)d_out;

    const int N = in_sizes[0] / 32;  // 80000

    char* ws = (char*)d_ws;
    double* sums1  = (double*)ws;         // 32
    double* sumsq1 = sums1 + 32;
    double* sums2  = sums1 + 64;
    double* sumsq2 = sums1 + 96;
    float* scale1 = (float*)(ws + 1024);
    float* shift1 = scale1 + 32;
    float* scale2 = scale1 + 64;
    float* shift2 = scale1 + 96;
    float* Ws1 = (float*)(ws + 4096);                 // 40960 floats = 160 KB
    float* Ws2 = Ws1 + RR * DD * TT * 8;
    float* s1  = Ws2 + RR * DD * TT * 8;
    float* sg2 = s1 + (size_t)N * 32;
    float* s2  = sg2 + (size_t)N * 32;

    int nBlocks = (N + 63) / 64;               // 1250

    // zero stats + both W spectra in one launch
    prep_kernel<<<40, 256, 0, stream>>>(W1, W2, Ws1, Ws2, (double*)ws, (float*)(ws + 1024));

    // ---- branch 1: fused gather+DFT+spectral-conv+pool+stats ----
    fused_conv_kernel<<<nBlocks, 256, 0, stream>>>(signal, bc_idx, bc_w, Ws1, b1, s1,
                                                   sums1, sumsq1, N);
    finalize_kernel<<<1, 32, 0, stream>>>(sums1, sumsq1, g1, be1, scale1, shift1, N);
    affine_relu_kernel<<<(N * 8 + 255) / 256, 256, 0, stream>>>(s1, scale1, shift1, sg2, N * 8);

    // ---- branch 2 ----
    fused_conv_kernel<<<nBlocks, 256, 0, stream>>>(sg2, bc_idx, bc_w, Ws2, b2, s2,
                                                   sums2, sumsq2, N);
    finalize_kernel<<<1, 32, 0, stream>>>(sums2, sumsq2, g2, be2, scale2, shift2, N);

    // ---- residual + relu ----
    final_kernel<<<(N * 8 + 255) / 256, 256, 0, stream>>>(s2, scale2, shift2, signal, out, N * 8);
}